// Round 1
// baseline (127.344 us; speedup 1.0000x reference)
//
#include <hip/hip_runtime.h>
#include <math.h>

#define CONS_RATE 0.001f
#define CLAMP_V   10.0f

__device__ __forceinline__ float fast_tanh(float x) {
    // tanh(x) = 1 - 2/(exp(2x)+1); exp overflow -> inf -> 1, underflow -> 0 -> -1 (both correct limits)
    float e = __expf(2.0f * x);
    return 1.0f - 2.0f * __builtin_amdgcn_rcpf(e + 1.0f);
}

__global__ __launch_bounds__(256) void ConsolidationDynamics_70068096467285_kernel(
    const float* __restrict__ w,
    const float* __restrict__ cs_p,
    const float* __restrict__ fs_p,
    const float* __restrict__ W1,   // (3,16) row-major
    const float* __restrict__ b1,   // (16,)
    const float* __restrict__ W2,   // (16,1)
    const float* __restrict__ b2,   // (1,)
    float* __restrict__ out,
    int n)                          // total elements
{
    __shared__ float s_a[16], s_c[16], s_w2[16], s_b2;

    const int t = threadIdx.x;
    if (t < 16) {
        const float cs = cs_p[0];
        const float fs = fs_p[0];
        s_a[t]  = W1[t];                                          // W1[0][j]
        s_c[t]  = fmaf(cs, W1[16 + t], fmaf(fs, W1[32 + t], b1[t]));
        s_w2[t] = W2[t];
        if (t == 0) s_b2 = b2[0];
    }
    __syncthreads();

    // Pull coefficients into registers once (LDS broadcast reads, conflict-free).
    float a[16], c[16], v2[16];
#pragma unroll
    for (int j = 0; j < 16; ++j) { a[j] = s_a[j]; c[j] = s_c[j]; v2[j] = s_w2[j]; }
    const float bb2 = s_b2;

    const int n4 = n >> 2;
    const float4* __restrict__ w4 = (const float4*)w;
    float4* __restrict__ o4 = (float4*)out;

    const int idx    = blockIdx.x * blockDim.x + threadIdx.x;
    const int stride = gridDim.x * blockDim.x;

    for (int i = idx; i < n4; i += stride) {
        const float4 wv = w4[i];
        float r[4] = {wv.x, wv.y, wv.z, wv.w};
        float o[4];
#pragma unroll
        for (int k = 0; k < 4; ++k) {
            float s = bb2;
#pragma unroll
            for (int j = 0; j < 16; ++j) {
                float h = fmaf(r[k], a[j], c[j]);
                h = fmaxf(h, 0.0f);
                s = fmaf(h, v2[j], s);
            }
            const float u  = fast_tanh(s);
            const float nw = fmaf(u, CONS_RATE, r[k]);
            o[k] = fminf(fmaxf(nw, -CLAMP_V), CLAMP_V);
        }
        o4[i] = make_float4(o[0], o[1], o[2], o[3]);
    }

    // Tail (n % 4 != 0) — not hit for 4096x4096 but kept for safety.
    for (int i = (n4 << 2) + idx; i < n; i += stride) {
        const float wv = w[i];
        float s = bb2;
#pragma unroll
        for (int j = 0; j < 16; ++j) {
            float h = fmaf(wv, a[j], c[j]);
            h = fmaxf(h, 0.0f);
            s = fmaf(h, v2[j], s);
        }
        const float u  = fast_tanh(s);
        const float nw = fmaf(u, CONS_RATE, wv);
        out[i] = fminf(fmaxf(nw, -CLAMP_V), CLAMP_V);
    }
}

extern "C" void kernel_launch(void* const* d_in, const int* in_sizes, int n_in,
                              void* d_out, int out_size, void* d_ws, size_t ws_size,
                              hipStream_t stream) {
    const float* w   = (const float*)d_in[0];
    const float* cs  = (const float*)d_in[1];
    const float* fs  = (const float*)d_in[2];
    const float* W1  = (const float*)d_in[3];
    const float* b1  = (const float*)d_in[4];
    const float* W2  = (const float*)d_in[5];
    const float* b2  = (const float*)d_in[6];
    float* out = (float*)d_out;

    const int n = in_sizes[0];
    const int block = 256;
    const int grid  = 2048;   // 8 blocks/CU-equivalent; grid-stride covers all of n

    ConsolidationDynamics_70068096467285_kernel<<<grid, block, 0, stream>>>(
        w, cs, fs, W1, b1, W2, b2, out, n);
}

// Round 2
// 125.357 us; speedup vs baseline: 1.0158x; 1.0158x over previous
//
#include <hip/hip_runtime.h>

#define CONS_RATE 0.001f
#define CLAMP_V   10.0f

// Per-element: out = clamp(w + 0.001*tanh(b2 + sum_j w2_j * relu(a_j*w + c_j)))
// where a_j = W1[0][j], c_j = cs*W1[1][j] + fs*W1[2][j] + b1[j] (scalars folded).

__global__ __launch_bounds__(256) void ConsolidationDynamics_70068096467285_kernel(
    const float* __restrict__ w,
    const float* __restrict__ cs_p,
    const float* __restrict__ fs_p,
    const float* __restrict__ W1,   // (3,16) row-major
    const float* __restrict__ b1,   // (16,)
    const float* __restrict__ W2,   // (16,1)
    const float* __restrict__ b2,   // (1,)
    float* __restrict__ out,
    int n)
{
    // Uniform-address loads -> scalar loads into SGPRs; no LDS, no arrays.
    const float cs  = cs_p[0];
    const float fs  = fs_p[0];
    const float bb2 = b2[0];

#define COEF(J) \
    const float a##J = W1[J]; \
    const float c##J = fmaf(cs, W1[16 + J], fmaf(fs, W1[32 + J], b1[J])); \
    const float v##J = W2[J];
    COEF(0)  COEF(1)  COEF(2)  COEF(3)
    COEF(4)  COEF(5)  COEF(6)  COEF(7)
    COEF(8)  COEF(9)  COEF(10) COEF(11)
    COEF(12) COEF(13) COEF(14) COEF(15)
#undef COEF

#define TERM(J, r, s) { float h = fmaf((r), a##J, c##J); h = fmaxf(h, 0.0f); (s) = fmaf(h, v##J, (s)); }
#define EVAL(r, d) { \
    float s = bb2; \
    TERM(0,(r),s)  TERM(1,(r),s)  TERM(2,(r),s)  TERM(3,(r),s)  \
    TERM(4,(r),s)  TERM(5,(r),s)  TERM(6,(r),s)  TERM(7,(r),s)  \
    TERM(8,(r),s)  TERM(9,(r),s)  TERM(10,(r),s) TERM(11,(r),s) \
    TERM(12,(r),s) TERM(13,(r),s) TERM(14,(r),s) TERM(15,(r),s) \
    float e  = __expf(2.0f * s); \
    float u  = 1.0f - 2.0f * __builtin_amdgcn_rcpf(e + 1.0f); \
    float nw = fmaf(u, CONS_RATE, (r)); \
    (d) = fminf(fmaxf(nw, -CLAMP_V), CLAMP_V); }

    const int n4  = n >> 2;
    const float4* __restrict__ w4 = (const float4*)w;
    float4* __restrict__ o4 = (float4*)out;

    const int nthreads = gridDim.x * blockDim.x;
    const int tid      = blockIdx.x * blockDim.x + threadIdx.x;
    const int step     = nthreads * 4;

    int i0 = tid;
    int i1 = tid + nthreads;
    int i2 = tid + 2 * nthreads;
    int i3 = tid + 3 * nthreads;

    // Main: 4 float4 (16 elements) in flight per thread for ILP/latency hiding.
    for (; i3 < n4; i0 += step, i1 += step, i2 += step, i3 += step) {
        const float4 A = w4[i0];
        const float4 B = w4[i1];
        const float4 C = w4[i2];
        const float4 D = w4[i3];
        float4 oA, oB, oC, oD;
        EVAL(A.x, oA.x) EVAL(A.y, oA.y) EVAL(A.z, oA.z) EVAL(A.w, oA.w)
        EVAL(B.x, oB.x) EVAL(B.y, oB.y) EVAL(B.z, oB.z) EVAL(B.w, oB.w)
        EVAL(C.x, oC.x) EVAL(C.y, oC.y) EVAL(C.z, oC.z) EVAL(C.w, oC.w)
        EVAL(D.x, oD.x) EVAL(D.y, oD.y) EVAL(D.z, oD.z) EVAL(D.w, oD.w)
        o4[i0] = oA;
        o4[i1] = oB;
        o4[i2] = oC;
        o4[i3] = oD;
    }
    // Remainder float4s.
    for (; i0 < n4; i0 += nthreads) {
        const float4 A = w4[i0];
        float4 oA;
        EVAL(A.x, oA.x) EVAL(A.y, oA.y) EVAL(A.z, oA.z) EVAL(A.w, oA.w)
        o4[i0] = oA;
    }
    // Scalar tail (n % 4).
    for (int i = (n4 << 2) + tid; i < n; i += nthreads) {
        const float r = w[i];
        float d;
        EVAL(r, d)
        out[i] = d;
    }
#undef EVAL
#undef TERM
}

extern "C" void kernel_launch(void* const* d_in, const int* in_sizes, int n_in,
                              void* d_out, int out_size, void* d_ws, size_t ws_size,
                              hipStream_t stream) {
    const float* w   = (const float*)d_in[0];
    const float* cs  = (const float*)d_in[1];
    const float* fs  = (const float*)d_in[2];
    const float* W1  = (const float*)d_in[3];
    const float* b1  = (const float*)d_in[4];
    const float* W2  = (const float*)d_in[5];
    const float* b2  = (const float*)d_in[6];
    float* out = (float*)d_out;

    const int n = in_sizes[0];
    // 4096 blocks x 256 threads x 16 elems/thread = 16.7M: covers 4096^2 in one batch.
    const int block = 256;
    const int grid  = 4096;

    ConsolidationDynamics_70068096467285_kernel<<<grid, block, 0, stream>>>(
        w, cs, fs, W1, b1, W2, b2, out, n);
}